// Round 3
// baseline (298.509 us; speedup 1.0000x reference)
//
#include <hip/hip_runtime.h>
#include <hip/hip_bf16.h>

#define DM 1024
#define SEQ 2048
#define NBATCH 4

using f32x4 = __attribute__((ext_vector_type(4))) float;
using s16x8 = __attribute__((ext_vector_type(8))) short;   // 8 bf16 in 4 VGPRs
using u16x4 = __attribute__((ext_vector_type(4))) unsigned short;
using u16x8 = __attribute__((ext_vector_type(8))) unsigned short;

__device__ __forceinline__ unsigned short f2bf(float f) {
  union { float f; unsigned u; } v; v.f = f;
  return (unsigned short)((v.u + 0x7fffu + ((v.u >> 16) & 1u)) >> 16);  // RNE
}

// async global->LDS, 16B per lane; LDS dest = wave-uniform base + lane*16
__device__ __forceinline__ void g2lds16(const void* g, void* l) {
  __builtin_amdgcn_global_load_lds(
      (const __attribute__((address_space(1))) void*)g,
      (__attribute__((address_space(3))) void*)l, 16, 0, 0);
}

// ---------------- conversion kernels ----------------

__global__ void cvt_x(const float* __restrict__ X, unsigned short* __restrict__ XB) {
  const int i = blockIdx.x * 256 + threadIdx.x;           // 8 elems/thread
  const f32x4* p = (const f32x4*)X;
  f32x4 a = p[2 * i], b = p[2 * i + 1];
  u16x8 o;
#pragma unroll
  for (int q = 0; q < 4; q++) { o[q] = f2bf(a[q]); o[4 + q] = f2bf(b[q]); }
  *(u16x8*)(XB + (size_t)i * 8) = o;
}

// WT[seg][n][k] = W_seg[k][n], bf16
__global__ void transpose_w(const float* __restrict__ Wq, const float* __restrict__ Wk,
                            const float* __restrict__ Wv, unsigned short* __restrict__ WT) {
  const int seg = blockIdx.z;
  const float* W = (seg == 0) ? Wq : (seg == 1) ? Wk : Wv;
  unsigned short* out = WT + (size_t)seg * DM * DM;
  __shared__ float t[32][33];
  const int k0 = blockIdx.y * 32, n0 = blockIdx.x * 32;
  const int tr = threadIdx.x >> 5, tc = threadIdx.x & 31;
#pragma unroll
  for (int p = 0; p < 4; p++) {
    int r = tr + p * 8;
    t[r][tc] = W[(size_t)(k0 + r) * DM + n0 + tc];
  }
  __syncthreads();
#pragma unroll
  for (int p = 0; p < 4; p++) {
    int r = tr + p * 8;
    out[(size_t)(n0 + r) * DM + k0 + tc] = f2bf(t[tc][r]);
  }
}

// ---------------- bf16 NT GEMM: 128x128 tile, BK=32, double-buffered LDS ----------------
// One barrier per K-iter.  Iter k:  barrier (drains staging of tile k issued
// last iter, which had a full compute phase in flight)  ->  issue async
// global_load_lds staging of tile k+1 into the OTHER buffer  ->  ds_read +
// MFMA tile k.  XOR swizzle (key = row&3, 4 chunks of 16B per 64B row) kept:
// fragment reads alias 2 lanes/bank-group, which is free (m136).
// MODE 0: QKV  (C0=Q bf16, C1=K bf16, C2=V^T bf16, biases)
// MODE 1: S = A·B^T * 1/32, fp32 (C0), per-batch via blockIdx.z
// MODE 2: O = P·Vt^T fp32 (C0), per-batch
template <int MODE, int LDA, int LDB, int KDIM>
__global__ void gemm_nt(const unsigned short* __restrict__ A,
                        const unsigned short* __restrict__ B,
                        void* __restrict__ C0,
                        unsigned short* __restrict__ C1,
                        unsigned short* __restrict__ C2,
                        const float* __restrict__ bq,
                        const float* __restrict__ bk,
                        const float* __restrict__ bv) {
  __shared__ unsigned short lA[2][128 * 32];   // 2 x 8 KB
  __shared__ unsigned short lB[2][128 * 32];   // 2 x 8 KB

  const int tid = threadIdx.x;
  const int w = tid >> 6;
  const int L = tid & 63;
  const int wm = w & 1, wn = w >> 1;
  const int bz = blockIdx.z;
  const int tileM = blockIdx.y * 128, tileN = blockIdx.x * 128;

  const unsigned short* Ab = A;
  const unsigned short* Bb = B;
  if (MODE == 1) { Ab += (size_t)bz * SEQ * DM; Bb += (size_t)bz * SEQ * DM; }
  if (MODE == 2) { Ab += (size_t)bz * SEQ * SEQ; Bb += (size_t)bz * DM * SEQ; }

  // staging: per matrix, 2 calls of 256 threads x 16B = 4 KB (64 rows) each.
  // thread t -> row = t>>2 (0..63), phys 16B-chunk = t&3 (HW-forced),
  // global chunk = (t&3) ^ (row&3)  [the XOR swizzle].
  const int srow = tid >> 2;                       // 0..63
  const int gch = (tid & 3) ^ (srow & 3);
  const char* gA0 = (const char*)(Ab + (size_t)(tileM + srow) * LDA) + gch * 16;
  const char* gB0 = (const char*)(Bb + (size_t)(tileN + srow) * LDB) + gch * 16;
  const size_t strA64 = (size_t)64 * LDA * 2;
  const size_t strB64 = (size_t)64 * LDB * 2;
  char* lAw = (char*)lA + w * 1024;   // wave-uniform; +b*8192 selects buffer
  char* lBw = (char*)lB + w * 1024;

#define STAGE(kt, b) do {                                          \
    const size_t kb_ = (size_t)(kt) * 64;                          \
    char* la_ = lAw + (b) * 8192;                                  \
    char* lb_ = lBw + (b) * 8192;                                  \
    g2lds16(gA0 + kb_,          la_);                              \
    g2lds16(gA0 + strA64 + kb_, la_ + 4096);                       \
    g2lds16(gB0 + kb_,          lb_);                              \
    g2lds16(gB0 + strB64 + kb_, lb_ + 4096);                       \
  } while (0)

  f32x4 acc[4][4];
#pragma unroll
  for (int i = 0; i < 4; i++)
#pragma unroll
    for (int j = 0; j < 4; j++) acc[i][j] = (f32x4){0.f, 0.f, 0.f, 0.f};

  const int rl = L & 15;                 // fragment row-within-16
  const int pc = ((L >> 4) ^ (rl & 3)) * 8;  // de-swizzled chunk offset (shorts)

  constexpr int NK = KDIM / 32;
  STAGE(0, 0);

  for (int k = 0; k < NK; ++k) {
    __syncthreads();                     // staging of tile k complete; prev reads done
    if (k + 1 < NK) STAGE(k + 1, (k + 1) & 1);   // async, overlaps the MFMAs below
    const unsigned short* cA = lA[k & 1];
    const unsigned short* cB = lB[k & 1];
    s16x8 av[4], bv4[4];
#pragma unroll
    for (int i = 0; i < 4; i++)
      av[i] = *(const s16x8*)&cA[(wm * 64 + i * 16 + rl) * 32 + pc];
#pragma unroll
    for (int j = 0; j < 4; j++)
      bv4[j] = *(const s16x8*)&cB[(wn * 64 + j * 16 + rl) * 32 + pc];
#pragma unroll
    for (int i = 0; i < 4; i++)
#pragma unroll
      for (int j = 0; j < 4; j++)
        acc[i][j] = __builtin_amdgcn_mfma_f32_16x16x32_bf16(av[i], bv4[j], acc[i][j], 0, 0, 0);
  }
#undef STAGE

  // epilogue: C/D layout col=lane&15, row=(lane>>4)*4+reg
#pragma unroll
  for (int i = 0; i < 4; i++) {
    const int gm0 = tileM + wm * 64 + i * 16 + (L >> 4) * 4;
#pragma unroll
    for (int j = 0; j < 4; j++) {
      const int gn = tileN + wn * 64 + j * 16 + (L & 15);
      if (MODE == 0) {
        const int seg = gn >> 10;          // block-uniform (128 | 1024)
        const int colin = gn & 1023;
        if (seg == 0) {
          const float bias = bq[colin];
          unsigned short* Q = (unsigned short*)C0;
#pragma unroll
          for (int r = 0; r < 4; r++) Q[(size_t)(gm0 + r) * DM + colin] = f2bf(acc[i][j][r] + bias);
        } else if (seg == 1) {
          const float bias = bk[colin];
#pragma unroll
          for (int r = 0; r < 4; r++) C1[(size_t)(gm0 + r) * DM + colin] = f2bf(acc[i][j][r] + bias);
        } else {                            // V, stored transposed: Vt[b][d][s]
          const float bias = bv[colin];
          u16x4 pk;
#pragma unroll
          for (int r = 0; r < 4; r++) pk[r] = f2bf(acc[i][j][r] + bias);
          const int b = gm0 >> 11, s0 = gm0 & 2047;
          *(u16x4*)(C2 + ((size_t)((b << 10) + colin)) * SEQ + s0) = pk;
        }
      } else if (MODE == 1) {
        float* S = (float*)C0 + (size_t)bz * SEQ * SEQ;
#pragma unroll
        for (int r = 0; r < 4; r++) S[(size_t)(gm0 + r) * SEQ + gn] = acc[i][j][r] * 0.03125f;
      } else {
        float* O = (float*)C0 + (size_t)bz * SEQ * DM;
#pragma unroll
        for (int r = 0; r < 4; r++) O[(size_t)(gm0 + r) * DM + gn] = acc[i][j][r];
      }
    }
  }
}

// ---------------- row softmax: S fp32 [8192 x 2048] -> P bf16 ----------------
__global__ void softmax_k(const float* __restrict__ S, unsigned short* __restrict__ P) {
  const int row = blockIdx.x;
  const float* src = S + (size_t)row * SEQ;
  const int t = threadIdx.x;
  f32x4 a = *(const f32x4*)(src + t * 8);
  f32x4 b = *(const f32x4*)(src + t * 8 + 4);
  float m = fmaxf(fmaxf(fmaxf(a[0], a[1]), fmaxf(a[2], a[3])),
                  fmaxf(fmaxf(b[0], b[1]), fmaxf(b[2], b[3])));
#pragma unroll
  for (int o = 32; o > 0; o >>= 1) m = fmaxf(m, __shfl_down(m, o, 64));
  __shared__ float redm[4], reds[4];
  if ((t & 63) == 0) redm[t >> 6] = m;
  __syncthreads();
  m = fmaxf(fmaxf(redm[0], redm[1]), fmaxf(redm[2], redm[3]));
  float e[8]; float s = 0.f;
#pragma unroll
  for (int q = 0; q < 4; q++) { e[q] = __expf(a[q] - m); s += e[q]; }
#pragma unroll
  for (int q = 0; q < 4; q++) { e[4 + q] = __expf(b[q] - m); s += e[4 + q]; }
#pragma unroll
  for (int o = 32; o > 0; o >>= 1) s += __shfl_down(s, o, 64);
  if ((t & 63) == 0) reds[t >> 6] = s;
  __syncthreads();
  s = reds[0] + reds[1] + reds[2] + reds[3];
  const float inv = 1.0f / s;
  u16x8 o8;
#pragma unroll
  for (int q = 0; q < 8; q++) o8[q] = f2bf(e[q] * inv);
  *(u16x8*)(P + (size_t)row * SEQ + t * 8) = o8;
}

// ---------------- launch ----------------
// ws layout (bytes):
//   xb  @ 0         : 16 MB  bf16 x            [8192,1024]
//   wt  @ 16777216  :  6 MB  bf16 W^T          [3072,1024]
//   qb  @ 23068672  : 16 MB  bf16 Q            [8192,1024]
//   kb  @ 39845888  : 16 MB  bf16 K            [8192,1024]
//   vt  @ 56623104  : 16 MB  bf16 V^T          [4][1024][2048]
//   S   @ 73400320  : 64 MB  fp32 scores       [4][2048][2048]
//   P   @ 140509184 : 32 MB  bf16 probs        [4][2048][2048]
// total 174063616 B (~166 MB)
extern "C" void kernel_launch(void* const* d_in, const int* in_sizes, int n_in,
                              void* d_out, int out_size, void* d_ws, size_t ws_size,
                              hipStream_t stream) {
  (void)in_sizes; (void)n_in; (void)out_size; (void)ws_size;
  const float* x  = (const float*)d_in[0];
  const float* Wq = (const float*)d_in[1];
  const float* bq = (const float*)d_in[2];
  const float* Wk = (const float*)d_in[3];
  const float* bk = (const float*)d_in[4];
  const float* Wv = (const float*)d_in[5];
  const float* bv = (const float*)d_in[6];
  float* out = (float*)d_out;
  char* ws = (char*)d_ws;
  unsigned short* xb = (unsigned short*)(ws + 0);
  unsigned short* wt = (unsigned short*)(ws + 16777216);
  unsigned short* qb = (unsigned short*)(ws + 23068672);
  unsigned short* kb = (unsigned short*)(ws + 39845888);
  unsigned short* vt = (unsigned short*)(ws + 56623104);
  float*          S  = (float*)         (ws + 73400320);
  unsigned short* P  = (unsigned short*)(ws + 140509184);

  cvt_x<<<4096, 256, 0, stream>>>(x, xb);
  transpose_w<<<dim3(32, 32, 3), 256, 0, stream>>>(Wq, Wk, Wv, wt);
  gemm_nt<0, 1024, 1024, 1024><<<dim3(24, 64, 1), 256, 0, stream>>>(
      xb, wt, (void*)qb, kb, vt, bq, bk, bv);
  gemm_nt<1, 1024, 1024, 1024><<<dim3(16, 16, 4), 256, 0, stream>>>(
      qb, kb, (void*)S, nullptr, nullptr, nullptr, nullptr, nullptr);
  softmax_k<<<8192, 256, 0, stream>>>(S, P);
  gemm_nt<2, 2048, 2048, 2048><<<dim3(8, 16, 4), 256, 0, stream>>>(
      P, vt, (void*)out, nullptr, nullptr, nullptr, nullptr, nullptr);
}

// Round 4
// 267.822 us; speedup vs baseline: 1.1146x; 1.1146x over previous
//
#include <hip/hip_runtime.h>
#include <hip/hip_bf16.h>

#define DM 1024
#define SEQ 2048
#define NBATCH 4

using f32x4 = __attribute__((ext_vector_type(4))) float;
using s16x8 = __attribute__((ext_vector_type(8))) short;   // 8 bf16 in 4 VGPRs
using u16x4 = __attribute__((ext_vector_type(4))) unsigned short;
using u16x8 = __attribute__((ext_vector_type(8))) unsigned short;

__device__ __forceinline__ unsigned short f2bf(float f) {
  union { float f; unsigned u; } v; v.f = f;
  return (unsigned short)((v.u + 0x7fffu + ((v.u >> 16) & 1u)) >> 16);  // RNE
}

// ---------------- conversion kernels ----------------

__global__ void cvt_x(const float* __restrict__ X, unsigned short* __restrict__ XB) {
  const int i = blockIdx.x * 256 + threadIdx.x;           // 8 elems/thread
  const f32x4* p = (const f32x4*)X;
  f32x4 a = p[2 * i], b = p[2 * i + 1];
  u16x8 o;
#pragma unroll
  for (int q = 0; q < 4; q++) { o[q] = f2bf(a[q]); o[4 + q] = f2bf(b[q]); }
  *(u16x8*)(XB + (size_t)i * 8) = o;
}

// WT[seg][n][k] = W_seg[k][n], bf16
__global__ void transpose_w(const float* __restrict__ Wq, const float* __restrict__ Wk,
                            const float* __restrict__ Wv, unsigned short* __restrict__ WT) {
  const int seg = blockIdx.z;
  const float* W = (seg == 0) ? Wq : (seg == 1) ? Wk : Wv;
  unsigned short* out = WT + (size_t)seg * DM * DM;
  __shared__ float t[32][33];
  const int k0 = blockIdx.y * 32, n0 = blockIdx.x * 32;
  const int tr = threadIdx.x >> 5, tc = threadIdx.x & 31;
#pragma unroll
  for (int p = 0; p < 4; p++) {
    int r = tr + p * 8;
    t[r][tc] = W[(size_t)(k0 + r) * DM + n0 + tc];
  }
  __syncthreads();
#pragma unroll
  for (int p = 0; p < 4; p++) {
    int r = tr + p * 8;
    out[(size_t)(n0 + r) * DM + k0 + tc] = f2bf(t[tc][r]);
  }
}

// ---------------- bf16 NT GEMM: 128x128 tile, BK=64, reg-staged pipeline ----------------
// AITER-style K-loop: buffer_load -> VGPR (no LDS dest => NO vmcnt drain at
// barriers) -> compute tile k from LDS -> raw s_barrier (lgkm only) ->
// ds_write tile k+1 (compiler's auto vmcnt wait lands HERE, after a full
// compute phase of latency cover) -> __syncthreads (drains nothing extra).
// XOR swizzle key = row&7 over 8 x 16B chunks per 128B row: conflict-free
// ds_write_b128 and ds_read_b128 (verified 0 conflicts in round 2).
// MODE 0: QKV  (C0=Q bf16, C1=K bf16, C2=V^T bf16, biases)
// MODE 1: S = A·B^T * 1/32, fp32 (C0), per-batch via blockIdx.z
// MODE 2: O = P·Vt^T fp32 (C0), per-batch
template <int MODE, int LDA, int LDB, int KDIM>
__global__ void gemm_nt(const unsigned short* __restrict__ A,
                        const unsigned short* __restrict__ B,
                        void* __restrict__ C0,
                        unsigned short* __restrict__ C1,
                        unsigned short* __restrict__ C2,
                        const float* __restrict__ bq,
                        const float* __restrict__ bk,
                        const float* __restrict__ bv) {
  __shared__ unsigned short lA[128 * 64];   // 16 KB
  __shared__ unsigned short lB[128 * 64];   // 16 KB

  const int tid = threadIdx.x;
  const int w = tid >> 6;
  const int L = tid & 63;
  const int wm = w & 1, wn = w >> 1;
  const int bz = blockIdx.z;
  const int tileM = blockIdx.y * 128, tileN = blockIdx.x * 128;

  const unsigned short* Ab = A;
  const unsigned short* Bb = B;
  if (MODE == 1) { Ab += (size_t)bz * SEQ * DM; Bb += (size_t)bz * SEQ * DM; }
  if (MODE == 2) { Ab += (size_t)bz * SEQ * SEQ; Bb += (size_t)bz * DM * SEQ; }

  // staging geometry: thread t -> row srow=t>>3 (0..31, +32*i), phys chunk t&7,
  // global chunk = (t&7) ^ (row&7); 32*i doesn't change row&7.
  const int srow = tid >> 3;
  const int pch = tid & 7;
  const int gch = pch ^ (srow & 7);
  const unsigned short* gA = Ab + (size_t)(tileM + srow) * LDA + gch * 8;
  const unsigned short* gB = Bb + (size_t)(tileN + srow) * LDB + gch * 8;
  unsigned short* wA = &lA[srow * 64 + pch * 8];
  unsigned short* wB = &lB[srow * 64 + pch * 8];

  u16x8 rA[4], rB[4];
#define LOADT(kt) do {                                                         \
    const size_t kk_ = (size_t)(kt) * 64;                                      \
    _Pragma("unroll")                                                          \
    for (int i_ = 0; i_ < 4; i_++) {                                           \
      rA[i_] = *(const u16x8*)(gA + (size_t)i_ * 32 * LDA + kk_);              \
      rB[i_] = *(const u16x8*)(gB + (size_t)i_ * 32 * LDB + kk_);              \
    }                                                                          \
  } while (0)
#define WRITET() do {                                                          \
    _Pragma("unroll")                                                          \
    for (int i_ = 0; i_ < 4; i_++) {                                           \
      *(u16x8*)(wA + i_ * 32 * 64) = rA[i_];                                   \
      *(u16x8*)(wB + i_ * 32 * 64) = rB[i_];                                   \
    }                                                                          \
  } while (0)

  f32x4 acc[4][4];
#pragma unroll
  for (int i = 0; i < 4; i++)
#pragma unroll
    for (int j = 0; j < 4; j++) acc[i][j] = (f32x4){0.f, 0.f, 0.f, 0.f};

  const int rl = L & 15;        // fragment row-within-16
  const int qh = L >> 4;        // fragment k-quad 0..3
  const int sw = L & 7;         // swizzle key = row&7 for fragment rows

  constexpr int NK = KDIM / 64;
  LOADT(0);
  WRITET();                      // compiler inserts vmcnt wait before the writes
  __syncthreads();               // vmcnt already drained; lgkm drain + barrier

  for (int k = 0; k < NK; ++k) {
    if (k + 1 < NK) LOADT(k + 1);     // global->VGPR, flies across compute phase

#pragma unroll
    for (int s = 0; s < 2; s++) {     // two K=32 halves of the BK=64 tile
      const int pc = ((s * 4 + qh) ^ sw) * 8;
      s16x8 av[4], bv4[4];
#pragma unroll
      for (int i = 0; i < 4; i++)
        av[i] = *(const s16x8*)&lA[(wm * 64 + i * 16 + rl) * 64 + pc];
#pragma unroll
      for (int j = 0; j < 4; j++)
        bv4[j] = *(const s16x8*)&lB[(wn * 64 + j * 16 + rl) * 64 + pc];
#pragma unroll
      for (int i = 0; i < 4; i++)
#pragma unroll
        for (int j = 0; j < 4; j++)
          acc[i][j] = __builtin_amdgcn_mfma_f32_16x16x32_bf16(av[i], bv4[j], acc[i][j], 0, 0, 0);
    }

    if (k + 1 < NK) {
      // raw barrier: all waves done READING tile k. lgkm(0) only — the k+1
      // global loads stay in flight (that's the whole point).
      __builtin_amdgcn_s_waitcnt(0xC07F);       // lgkmcnt(0), vmcnt/exp no-wait
      __builtin_amdgcn_sched_barrier(0);
      __builtin_amdgcn_s_barrier();
      __builtin_amdgcn_sched_barrier(0);
      WRITET();                                  // vmcnt wait auto-inserted here
      __syncthreads();                           // tile k+1 visible
    }
  }
#undef LOADT
#undef WRITET

  // epilogue: C/D layout col=lane&15, row=(lane>>4)*4+reg
#pragma unroll
  for (int i = 0; i < 4; i++) {
    const int gm0 = tileM + wm * 64 + i * 16 + (L >> 4) * 4;
#pragma unroll
    for (int j = 0; j < 4; j++) {
      const int gn = tileN + wn * 64 + j * 16 + (L & 15);
      if (MODE == 0) {
        const int seg = gn >> 10;          // block-uniform (128 | 1024)
        const int colin = gn & 1023;
        if (seg == 0) {
          const float bias = bq[colin];
          unsigned short* Q = (unsigned short*)C0;
#pragma unroll
          for (int r = 0; r < 4; r++) Q[(size_t)(gm0 + r) * DM + colin] = f2bf(acc[i][j][r] + bias);
        } else if (seg == 1) {
          const float bias = bk[colin];
#pragma unroll
          for (int r = 0; r < 4; r++) C1[(size_t)(gm0 + r) * DM + colin] = f2bf(acc[i][j][r] + bias);
        } else {                            // V, stored transposed: Vt[b][d][s]
          const float bias = bv[colin];
          u16x4 pk;
#pragma unroll
          for (int r = 0; r < 4; r++) pk[r] = f2bf(acc[i][j][r] + bias);
          const int b = gm0 >> 11, s0 = gm0 & 2047;
          *(u16x4*)(C2 + ((size_t)((b << 10) + colin)) * SEQ + s0) = pk;
        }
      } else if (MODE == 1) {
        float* S = (float*)C0 + (size_t)bz * SEQ * SEQ;
#pragma unroll
        for (int r = 0; r < 4; r++) S[(size_t)(gm0 + r) * SEQ + gn] = acc[i][j][r] * 0.03125f;
      } else {
        float* O = (float*)C0 + (size_t)bz * SEQ * DM;
#pragma unroll
        for (int r = 0; r < 4; r++) O[(size_t)(gm0 + r) * DM + gn] = acc[i][j][r];
      }
    }
  }
}

// ---------------- row softmax: S fp32 [8192 x 2048] -> P bf16 ----------------
__global__ void softmax_k(const float* __restrict__ S, unsigned short* __restrict__ P) {
  const int row = blockIdx.x;
  const float* src = S + (size_t)row * SEQ;
  const int t = threadIdx.x;
  f32x4 a = *(const f32x4*)(src + t * 8);
  f32x4 b = *(const f32x4*)(src + t * 8 + 4);
  float m = fmaxf(fmaxf(fmaxf(a[0], a[1]), fmaxf(a[2], a[3])),
                  fmaxf(fmaxf(b[0], b[1]), fmaxf(b[2], b[3])));
#pragma unroll
  for (int o = 32; o > 0; o >>= 1) m = fmaxf(m, __shfl_down(m, o, 64));
  __shared__ float redm[4], reds[4];
  if ((t & 63) == 0) redm[t >> 6] = m;
  __syncthreads();
  m = fmaxf(fmaxf(redm[0], redm[1]), fmaxf(redm[2], redm[3]));
  float e[8]; float s = 0.f;
#pragma unroll
  for (int q = 0; q < 4; q++) { e[q] = __expf(a[q] - m); s += e[q]; }
#pragma unroll
  for (int q = 0; q < 4; q++) { e[4 + q] = __expf(b[q] - m); s += e[4 + q]; }
#pragma unroll
  for (int o = 32; o > 0; o >>= 1) s += __shfl_down(s, o, 64);
  if ((t & 63) == 0) reds[t >> 6] = s;
  __syncthreads();
  s = reds[0] + reds[1] + reds[2] + reds[3];
  const float inv = 1.0f / s;
  u16x8 o8;
#pragma unroll
  for (int q = 0; q < 8; q++) o8[q] = f2bf(e[q] * inv);
  *(u16x8*)(P + (size_t)row * SEQ + t * 8) = o8;
}

// ---------------- launch ----------------
// ws layout (bytes):
//   xb  @ 0         : 16 MB  bf16 x            [8192,1024]
//   wt  @ 16777216  :  6 MB  bf16 W^T          [3072,1024]
//   qb  @ 23068672  : 16 MB  bf16 Q            [8192,1024]
//   kb  @ 39845888  : 16 MB  bf16 K            [8192,1024]
//   vt  @ 56623104  : 16 MB  bf16 V^T          [4][1024][2048]
//   S   @ 73400320  : 64 MB  fp32 scores       [4][2048][2048]
//   P   @ 140509184 : 32 MB  bf16 probs        [4][2048][2048]
// total 174063616 B (~166 MB)
extern "C" void kernel_launch(void* const* d_in, const int* in_sizes, int n_in,
                              void* d_out, int out_size, void* d_ws, size_t ws_size,
                              hipStream_t stream) {
  (void)in_sizes; (void)n_in; (void)out_size; (void)ws_size;
  const float* x  = (const float*)d_in[0];
  const float* Wq = (const float*)d_in[1];
  const float* bq = (const float*)d_in[2];
  const float* Wk = (const float*)d_in[3];
  const float* bk = (const float*)d_in[4];
  const float* Wv = (const float*)d_in[5];
  const float* bv = (const float*)d_in[6];
  float* out = (float*)d_out;
  char* ws = (char*)d_ws;
  unsigned short* xb = (unsigned short*)(ws + 0);
  unsigned short* wt = (unsigned short*)(ws + 16777216);
  unsigned short* qb = (unsigned short*)(ws + 23068672);
  unsigned short* kb = (unsigned short*)(ws + 39845888);
  unsigned short* vt = (unsigned short*)(ws + 56623104);
  float*          S  = (float*)         (ws + 73400320);
  unsigned short* P  = (unsigned short*)(ws + 140509184);

  cvt_x<<<4096, 256, 0, stream>>>(x, xb);
  transpose_w<<<dim3(32, 32, 3), 256, 0, stream>>>(Wq, Wk, Wv, wt);
  gemm_nt<0, 1024, 1024, 1024><<<dim3(24, 64, 1), 256, 0, stream>>>(
      xb, wt, (void*)qb, kb, vt, bq, bk, bv);
  gemm_nt<1, 1024, 1024, 1024><<<dim3(16, 16, 4), 256, 0, stream>>>(
      qb, kb, (void*)S, nullptr, nullptr, nullptr, nullptr, nullptr);
  softmax_k<<<8192, 256, 0, stream>>>(S, P);
  gemm_nt<2, 2048, 2048, 2048><<<dim3(8, 16, 4), 256, 0, stream>>>(
      P, vt, (void*)out, nullptr, nullptr, nullptr, nullptr, nullptr);
}